// Round 3
// baseline (527.753 us; speedup 1.0000x reference)
//
#include <hip/hip_runtime.h>

#define EPSF 1e-9f

typedef __attribute__((ext_vector_type(8))) short short8;
typedef __attribute__((ext_vector_type(4))) float f32x4;
typedef __attribute__((ext_vector_type(4))) unsigned int u32x4;
typedef __attribute__((ext_vector_type(2))) unsigned int u32x2;

__device__ __forceinline__ unsigned pkbf(float lo, float hi) {
  unsigned r;
  asm("v_cvt_pk_bf16_f32 %0, %1, %2" : "=v"(r) : "v"(lo), "v"(hi));
  return r;
}
__device__ __forceinline__ short8 mk8(unsigned a, unsigned b, unsigned c, unsigned d) {
  u32x4 u = {a, b, c, d};
  return __builtin_bit_cast(short8, u);
}

// ---------------- k_s: s[b,n] = (si_r, si_i, sj_r, sj_i); 8 lanes per row
__global__ __launch_bounds__(256) void k_s(
    const float* __restrict__ Xr, const float* __restrict__ Xi,
    const float* __restrict__ War, const float* __restrict__ Wai,
    float4* __restrict__ s4, float2* __restrict__ sj2)
{
  int t = threadIdx.x;
  int nf = blockIdx.x * 32 + (t >> 3);   // flat b*512+n
  int c0 = (t & 7) * 8;
  const f32x4* xr = (const f32x4*)(Xr + (size_t)nf * 64 + c0);
  const f32x4* xi = (const f32x4*)(Xi + (size_t)nf * 64 + c0);
  const f32x4* w1r = (const f32x4*)(War + c0);
  const f32x4* w2r = (const f32x4*)(War + 64 + c0);
  const f32x4* w1i = (const f32x4*)(Wai + c0);
  const f32x4* w2i = (const f32x4*)(Wai + 64 + c0);
  float sir = 0.f, sii = 0.f, sjr = 0.f, sji = 0.f;
#pragma unroll
  for (int h = 0; h < 2; ++h) {
    f32x4 a = xr[h], bb = xi[h];
    f32x4 u1r = w1r[h], u1i = w1i[h], u2r = w2r[h], u2i = w2i[h];
#pragma unroll
    for (int e = 0; e < 4; ++e) {
      sir += a[e] * u1r[e] - bb[e] * u1i[e];
      sii += a[e] * u1i[e] + bb[e] * u1r[e];
      sjr += a[e] * u2r[e] - bb[e] * u2i[e];
      sji += a[e] * u2i[e] + bb[e] * u2r[e];
    }
  }
#pragma unroll
  for (int off = 1; off < 8; off <<= 1) {
    sir += __shfl_xor(sir, off);
    sii += __shfl_xor(sii, off);
    sjr += __shfl_xor(sjr, off);
    sji += __shfl_xor(sji, off);
  }
  if ((t & 7) == 0) {
    s4[nf] = make_float4(sir, sii, sjr, sji);
    sj2[nf] = make_float2(sjr, sji);
  }
}

// ---------------- k_stats: per-(b,i) (max_r, 1/sum_r, max_i, 1/sum_i)
__global__ __launch_bounds__(256) void k_stats(
    const float4* __restrict__ s4, const float2* __restrict__ sj2,
    const float* __restrict__ bar, const float* __restrict__ bai,
    const float* __restrict__ modbp, float4* __restrict__ stats)
{
  __shared__ float2 sh[512];
  int t = threadIdx.x;
  int b = blockIdx.x >> 4;
  int i0 = (blockIdx.x & 15) * 32;
  sh[t] = sj2[(size_t)b * 512 + t];
  sh[t + 256] = sj2[(size_t)b * 512 + t + 256];
  __syncthreads();
  float ba_r = bar[0], ba_i = bai[0], modb = modbp[0];
  int i = i0 + (t >> 3), jl = t & 7;
  float4 sv = s4[(size_t)b * 512 + i];
  float sirb = sv.x + ba_r, siib = sv.y + ba_i;
  float mr = -1e30f, mi = -1e30f;
  for (int jj = 0; jj < 64; ++jj) {
    float2 sj = sh[jl * 64 + jj];
    float scr = sirb + sj.x, sci = siib + sj.y;
    float mag = sqrtf(scr * scr + sci * sci);
    float sc = fmaxf(mag + modb, 0.f) * __builtin_amdgcn_rcpf(mag + EPSF);
    mr = fmaxf(mr, scr * sc);
    mi = fmaxf(mi, sci * sc);
  }
#pragma unroll
  for (int off = 1; off < 8; off <<= 1) {
    mr = fmaxf(mr, __shfl_xor(mr, off));
    mi = fmaxf(mi, __shfl_xor(mi, off));
  }
  float er = 0.f, ei = 0.f;
  for (int jj = 0; jj < 64; ++jj) {
    float2 sj = sh[jl * 64 + jj];
    float scr = sirb + sj.x, sci = siib + sj.y;
    float mag = sqrtf(scr * scr + sci * sci);
    float sc = fmaxf(mag + modb, 0.f) * __builtin_amdgcn_rcpf(mag + EPSF);
    er += __expf(scr * sc - mr);
    ei += __expf(sci * sc - mi);
  }
#pragma unroll
  for (int off = 1; off < 8; off <<= 1) {
    er += __shfl_xor(er, off);
    ei += __shfl_xor(ei, off);
  }
  if (jl == 0)
    stats[(size_t)b * 512 + i] = make_float4(mr, 1.f / er, mi, 1.f / ei);
}

// ---------------- k_y: Y[b,k] = X[b] @ W[k] (complex), written to ws in
// B-fragment layout, bf16: line = (((b*5+k)*2+part)*16+js)*4+osub, 64 lanes x 16B
__global__ __launch_bounds__(256) void k_y(
    const float* __restrict__ Xr, const float* __restrict__ Xi,
    const float* __restrict__ Wr, const float* __restrict__ Wi,
    u32x4* __restrict__ yfrag)
{
  __shared__ __align__(16) short WtR[64 * 72];     // [o][c] pad 72
  __shared__ __align__(16) short WtI[64 * 72];
  __shared__ __align__(16) short Yt[4][2][64 * 24]; // per-wave [o][jj] pad 24
  int bk = blockIdx.x;
  int b = bk / 5, k = bk % 5;
  int t = threadIdx.x;
  {
    int o = t & 63, cbase = (t >> 6) * 16;
    const float* wr = Wr + (size_t)k * 4096;
    const float* wi = Wi + (size_t)k * 4096;
#pragma unroll
    for (int cc = 0; cc < 16; cc += 2) {
      int c = cbase + cc;
      *(unsigned*)&WtR[o * 72 + c] = pkbf(wr[c * 64 + o], wr[(c + 1) * 64 + o]);
      *(unsigned*)&WtI[o * 72 + c] = pkbf(wi[c * 64 + o], wi[(c + 1) * 64 + o]);
    }
  }
  __syncthreads();
  int w = t >> 6, l = t & 63;
  int lane15 = l & 15, quad = l >> 4;
  short* ytR = &Yt[w][0][0];
  short* ytI = &Yt[w][1][0];
  for (int qq = 0; qq < 8; ++qq) {
    int q = w * 8 + qq;
    int j = q * 16 + lane15;
    const f32x4* pxr = (const f32x4*)(Xr + ((size_t)b * 512 + j) * 64 + quad * 8);
    const f32x4* pxi = (const f32x4*)(Xi + ((size_t)b * 512 + j) * 64 + quad * 8);
    f32x4 xr0 = pxr[0], xr1 = pxr[1], xr8 = pxr[8], xr9 = pxr[9];
    f32x4 xi0 = pxi[0], xi1 = pxi[1], xi8 = pxi[8], xi9 = pxi[9];
    short8 axr[2], axi[2];
    axr[0] = mk8(pkbf(xr0[0], xr0[1]), pkbf(xr0[2], xr0[3]), pkbf(xr1[0], xr1[1]), pkbf(xr1[2], xr1[3]));
    axr[1] = mk8(pkbf(xr8[0], xr8[1]), pkbf(xr8[2], xr8[3]), pkbf(xr9[0], xr9[1]), pkbf(xr9[2], xr9[3]));
    axi[0] = mk8(pkbf(xi0[0], xi0[1]), pkbf(xi0[2], xi0[3]), pkbf(xi1[0], xi1[1]), pkbf(xi1[2], xi1[3]));
    axi[1] = mk8(pkbf(xi8[0], xi8[1]), pkbf(xi8[2], xi8[3]), pkbf(xi9[0], xi9[1]), pkbf(xi9[2], xi9[3]));
    f32x4 aR1[4], aR2[4], aI[4];
#pragma unroll
    for (int os = 0; os < 4; ++os) {
      aR1[os] = f32x4{0.f, 0.f, 0.f, 0.f};
      aR2[os] = f32x4{0.f, 0.f, 0.f, 0.f};
      aI[os] = f32x4{0.f, 0.f, 0.f, 0.f};
    }
#pragma unroll
    for (int kc = 0; kc < 2; ++kc) {
#pragma unroll
      for (int os = 0; os < 4; ++os) {
        int widx = (os * 16 + lane15) * 72 + kc * 32 + quad * 8;
        short8 wrF = *(const short8*)&WtR[widx];
        short8 wiF = *(const short8*)&WtI[widx];
        aR1[os] = __builtin_amdgcn_mfma_f32_16x16x32_bf16(axr[kc], wrF, aR1[os], 0, 0, 0);
        aR2[os] = __builtin_amdgcn_mfma_f32_16x16x32_bf16(axi[kc], wiF, aR2[os], 0, 0, 0);
        aI[os]  = __builtin_amdgcn_mfma_f32_16x16x32_bf16(axr[kc], wiF, aI[os], 0, 0, 0);
        aI[os]  = __builtin_amdgcn_mfma_f32_16x16x32_bf16(axi[kc], wrF, aI[os], 0, 0, 0);
      }
    }
#pragma unroll
    for (int os = 0; os < 4; ++os) {
      f32x4 R = aR1[os] - aR2[os];
      f32x4 I = aI[os];
      int ya = (os * 16 + lane15) * 24 + quad * 4;
      *(u32x2*)&ytR[ya] = u32x2{pkbf(R[0], R[1]), pkbf(R[2], R[3])};
      *(u32x2*)&ytI[ya] = u32x2{pkbf(I[0], I[1]), pkbf(I[2], I[3])};
    }
#pragma unroll
    for (int part = 0; part < 2; ++part) {
      const short* yt = part ? ytI : ytR;
#pragma unroll
      for (int h = 0; h < 2; ++h) {
        short8 unit = *(const short8*)&yt[l * 24 + h * 8];
        size_t line = (((size_t)(b * 5 + k) * 2 + part) * 16 + (q >> 1)) * 4 + (l >> 4);
        size_t idx = line * 64 + ((q & 1) * 2 + h) * 16 + (l & 15);
        yfrag[idx] = __builtin_bit_cast(u32x4, unit);
      }
    }
  }
}

// ---------------- k_main: out[b, i-tile(16)] — 4 waves/block, j-split contraction.
// Wave w handles js = 4w..4w+3; partial accumulators tree-reduced through LDS.
__global__ __launch_bounds__(256, 6) void k_main(
    const float* __restrict__ lapr, const float* __restrict__ lapi,
    const float4* __restrict__ s4, const float4* __restrict__ stats,
    const float2* __restrict__ sj2, const u32x4* __restrict__ yfrag,
    const float* __restrict__ bar, const float* __restrict__ bai,
    const float* __restrict__ modbp,
    float* __restrict__ out_r, float* __restrict__ out_i)
{
  __shared__ __align__(16) f32x4 red[2][64][8];   // 16 KB tree-reduce buffer

  int g = blockIdx.x;
  int b = (g & 7) + ((g >> 8) << 3);   // XCD swizzle: same-b i-tiles on one XCD
  int it = (g >> 3) & 31;
  int t = threadIdx.x;
  int w = t >> 6;                       // wave 0..3
  int l = t & 63;
  int lane15 = l & 15, quad = l >> 4;
  int gi = it * 16 + lane15;

  float ba_r = bar[0], ba_i = bai[0], modb = modbp[0];
  float4 sv = s4[(size_t)b * 512 + gi];
  float4 st = stats[(size_t)b * 512 + gi];
  float sirb = sv.x + ba_r, siib = sv.y + ba_i;
  float maxr = st.x, rsr = st.y, maxi = st.z, rsi = st.w;

  f32x4 accR1[4], accR2[4], accI[4];
#pragma unroll
  for (int os = 0; os < 4; ++os) {
    accR1[os] = f32x4{0.f, 0.f, 0.f, 0.f};
    accR2[os] = f32x4{0.f, 0.f, 0.f, 0.f};
    accI[os] = f32x4{0.f, 0.f, 0.f, 0.f};
  }

  const size_t NN = (size_t)512 * 512;
  const float* lapr_b = lapr + ((size_t)b * 5 * 512 + gi) * 512;
  const float* lapi_b = lapi + ((size_t)b * 5 * 512 + gi) * 512;

  for (int jsw = 0; jsw < 4; ++jsw) {
    int js = w * 4 + jsw;
    int jq = js * 32 + quad * 8;
    float2 sj[8];
#pragma unroll
    for (int e = 0; e < 8; ++e) sj[e] = sj2[(size_t)b * 512 + jq + e];
    f32x4 LRv[5][2], LIv[5][2];
#pragma unroll
    for (int k = 0; k < 5; ++k) {
      const f32x4* pr = (const f32x4*)(lapr_b + (size_t)k * NN + jq);
      const f32x4* pi_ = (const f32x4*)(lapi_b + (size_t)k * NN + jq);
      LRv[k][0] = __builtin_nontemporal_load(pr);
      LRv[k][1] = __builtin_nontemporal_load(pr + 1);
      LIv[k][0] = __builtin_nontemporal_load(pi_);
      LIv[k][1] = __builtin_nontemporal_load(pi_ + 1);
    }
    float ar[8], ai[8];
#pragma unroll
    for (int e = 0; e < 8; ++e) {
      float scr = sirb + sj[e].x;
      float sci = siib + sj[e].y;
      float mag = sqrtf(scr * scr + sci * sci);
      float sc = fmaxf(mag + modb, 0.f) * __builtin_amdgcn_rcpf(mag + EPSF);
      ar[e] = __expf(scr * sc - maxr) * rsr;
      ai[e] = __expf(sci * sc - maxi) * rsi;
    }
#pragma unroll
    for (int k = 0; k < 5; ++k) {
      const u32x4* y0 = yfrag + ((size_t)(b * 5 + k) * 128 + js * 4) * 64 + l;
      u32x4 bR[4], bI[4];
#pragma unroll
      for (int os = 0; os < 4; ++os) {
        bR[os] = y0[os * 64];
        bI[os] = y0[4096 + os * 64];
      }
      float lrv[8], liv[8];
#pragma unroll
      for (int h = 0; h < 2; ++h)
#pragma unroll
        for (int e2 = 0; e2 < 4; ++e2) {
          float grv = LRv[k][h][e2], giv = LIv[k][h][e2];
          int e = h * 4 + e2;
          lrv[e] = grv * ar[e] - giv * ai[e];
          liv[e] = grv * ai[e] + giv * ar[e];
        }
      short8 Ar = mk8(pkbf(lrv[0], lrv[1]), pkbf(lrv[2], lrv[3]), pkbf(lrv[4], lrv[5]), pkbf(lrv[6], lrv[7]));
      short8 Ai = mk8(pkbf(liv[0], liv[1]), pkbf(liv[2], liv[3]), pkbf(liv[4], liv[5]), pkbf(liv[6], liv[7]));
#pragma unroll
      for (int os = 0; os < 4; ++os) {
        short8 br8 = __builtin_bit_cast(short8, bR[os]);
        short8 bi8 = __builtin_bit_cast(short8, bI[os]);
        accR1[os] = __builtin_amdgcn_mfma_f32_16x16x32_bf16(Ar, br8, accR1[os], 0, 0, 0);
        accR2[os] = __builtin_amdgcn_mfma_f32_16x16x32_bf16(Ai, bi8, accR2[os], 0, 0, 0);
        accI[os]  = __builtin_amdgcn_mfma_f32_16x16x32_bf16(Ar, bi8, accI[os], 0, 0, 0);
        accI[os]  = __builtin_amdgcn_mfma_f32_16x16x32_bf16(Ai, br8, accI[os], 0, 0, 0);
      }
    }
  }

  // ---- combine real part, then tree-reduce partial sums across the 4 waves
  f32x4 R[4], I[4];
#pragma unroll
  for (int os = 0; os < 4; ++os) {
    R[os] = accR1[os] - accR2[os];
    I[os] = accI[os];
  }
  if (w >= 2) {
#pragma unroll
    for (int os = 0; os < 4; ++os) {
      red[w - 2][l][os] = R[os];
      red[w - 2][l][4 + os] = I[os];
    }
  }
  __syncthreads();
  if (w < 2) {
#pragma unroll
    for (int os = 0; os < 4; ++os) {
      R[os] += red[w][l][os];
      I[os] += red[w][l][4 + os];
    }
  }
  __syncthreads();
  if (w == 1) {
#pragma unroll
    for (int os = 0; os < 4; ++os) {
      red[0][l][os] = R[os];
      red[0][l][4 + os] = I[os];
    }
  }
  __syncthreads();
  if (w == 0) {
#pragma unroll
    for (int os = 0; os < 4; ++os) {
      R[os] += red[0][l][os];
      I[os] += red[0][l][4 + os];
      int oc = os * 16 + lane15;
#pragma unroll
      for (int r = 0; r < 4; ++r) {
        size_t oidx = ((size_t)b * 512 + it * 16 + quad * 4 + r) * 64 + oc;
        out_r[oidx] = R[os][r];
        out_i[oidx] = I[os][r];
      }
    }
  }
}

extern "C" void kernel_launch(void* const* d_in, const int* in_sizes, int n_in,
                              void* d_out, int out_size, void* d_ws, size_t ws_size,
                              hipStream_t stream) {
  const float* Xr = (const float*)d_in[0];
  const float* Xi = (const float*)d_in[1];
  const float* lapr = (const float*)d_in[2];
  const float* lapi = (const float*)d_in[3];
  const float* War = (const float*)d_in[4];
  const float* Wai = (const float*)d_in[5];
  const float* bar = (const float*)d_in[6];
  const float* bai = (const float*)d_in[7];
  const float* modb = (const float*)d_in[8];
  const float* Wr = (const float*)d_in[9];
  const float* Wi = (const float*)d_in[10];

  // ws layout: s4 384KB | stats 384KB | sj2 192KB | yfrag 30MB  (total ~31.7MB)
  char* wsb = (char*)d_ws;
  float4* s4 = (float4*)wsb;
  float4* stats = (float4*)(wsb + 393216);
  float2* sj2 = (float2*)(wsb + 786432);
  u32x4* yfrag = (u32x4*)(wsb + 983040);

  float* out_r = (float*)d_out;
  float* out_i = out_r + (size_t)48 * 512 * 64;

  k_s<<<768, 256, 0, stream>>>(Xr, Xi, War, Wai, s4, sj2);
  k_stats<<<768, 256, 0, stream>>>(s4, sj2, bar, bai, modb, stats);
  k_y<<<240, 256, 0, stream>>>(Xr, Xi, Wr, Wi, yfrag);
  k_main<<<1536, 256, 0, stream>>>(lapr, lapi, s4, stats, sj2, yfrag,
                                   bar, bai, modb, out_r, out_i);
}

// Round 4
// 239.251 us; speedup vs baseline: 2.2059x; 2.2059x over previous
//
#include <hip/hip_runtime.h>

#define EPSF 1e-9f

typedef __attribute__((ext_vector_type(8))) short short8;
typedef __attribute__((ext_vector_type(4))) float f32x4;
typedef __attribute__((ext_vector_type(4))) unsigned int u32x4;
typedef __attribute__((ext_vector_type(2))) unsigned int u32x2;

__device__ __forceinline__ unsigned pkbf(float lo, float hi) {
  unsigned r;
  asm("v_cvt_pk_bf16_f32 %0, %1, %2" : "=v"(r) : "v"(lo), "v"(hi));
  return r;
}
__device__ __forceinline__ short8 mk8(unsigned a, unsigned b, unsigned c, unsigned d) {
  u32x4 u = {a, b, c, d};
  return __builtin_bit_cast(short8, u);
}

// ---------------- k_s: s[b,n] = (si_r, si_i, sj_r, sj_i); 8 lanes per row
__global__ __launch_bounds__(256) void k_s(
    const float* __restrict__ Xr, const float* __restrict__ Xi,
    const float* __restrict__ War, const float* __restrict__ Wai,
    float4* __restrict__ s4, float2* __restrict__ sj2)
{
  int t = threadIdx.x;
  int nf = blockIdx.x * 32 + (t >> 3);   // flat b*512+n
  int c0 = (t & 7) * 8;
  const f32x4* xr = (const f32x4*)(Xr + (size_t)nf * 64 + c0);
  const f32x4* xi = (const f32x4*)(Xi + (size_t)nf * 64 + c0);
  const f32x4* w1r = (const f32x4*)(War + c0);
  const f32x4* w2r = (const f32x4*)(War + 64 + c0);
  const f32x4* w1i = (const f32x4*)(Wai + c0);
  const f32x4* w2i = (const f32x4*)(Wai + 64 + c0);
  float sir = 0.f, sii = 0.f, sjr = 0.f, sji = 0.f;
#pragma unroll
  for (int h = 0; h < 2; ++h) {
    f32x4 a = xr[h], bb = xi[h];
    f32x4 u1r = w1r[h], u1i = w1i[h], u2r = w2r[h], u2i = w2i[h];
#pragma unroll
    for (int e = 0; e < 4; ++e) {
      sir += a[e] * u1r[e] - bb[e] * u1i[e];
      sii += a[e] * u1i[e] + bb[e] * u1r[e];
      sjr += a[e] * u2r[e] - bb[e] * u2i[e];
      sji += a[e] * u2i[e] + bb[e] * u2r[e];
    }
  }
#pragma unroll
  for (int off = 1; off < 8; off <<= 1) {
    sir += __shfl_xor(sir, off);
    sii += __shfl_xor(sii, off);
    sjr += __shfl_xor(sjr, off);
    sji += __shfl_xor(sji, off);
  }
  if ((t & 7) == 0) {
    s4[nf] = make_float4(sir, sii, sjr, sji);
    sj2[nf] = make_float2(sjr, sji);
  }
}

// ---------------- k_stats: per-(b,i) (max_r, 1/sum_r, max_i, 1/sum_i)
__global__ __launch_bounds__(256) void k_stats(
    const float4* __restrict__ s4, const float2* __restrict__ sj2,
    const float* __restrict__ bar, const float* __restrict__ bai,
    const float* __restrict__ modbp, float4* __restrict__ stats)
{
  __shared__ float2 sh[512];
  int t = threadIdx.x;
  int b = blockIdx.x >> 4;
  int i0 = (blockIdx.x & 15) * 32;
  sh[t] = sj2[(size_t)b * 512 + t];
  sh[t + 256] = sj2[(size_t)b * 512 + t + 256];
  __syncthreads();
  float ba_r = bar[0], ba_i = bai[0], modb = modbp[0];
  int i = i0 + (t >> 3), jl = t & 7;
  float4 sv = s4[(size_t)b * 512 + i];
  float sirb = sv.x + ba_r, siib = sv.y + ba_i;
  float mr = -1e30f, mi = -1e30f;
  for (int jj = 0; jj < 64; ++jj) {
    float2 sj = sh[jl * 64 + jj];
    float scr = sirb + sj.x, sci = siib + sj.y;
    float mag = sqrtf(scr * scr + sci * sci);
    float sc = fmaxf(mag + modb, 0.f) * __builtin_amdgcn_rcpf(mag + EPSF);
    mr = fmaxf(mr, scr * sc);
    mi = fmaxf(mi, sci * sc);
  }
#pragma unroll
  for (int off = 1; off < 8; off <<= 1) {
    mr = fmaxf(mr, __shfl_xor(mr, off));
    mi = fmaxf(mi, __shfl_xor(mi, off));
  }
  float er = 0.f, ei = 0.f;
  for (int jj = 0; jj < 64; ++jj) {
    float2 sj = sh[jl * 64 + jj];
    float scr = sirb + sj.x, sci = siib + sj.y;
    float mag = sqrtf(scr * scr + sci * sci);
    float sc = fmaxf(mag + modb, 0.f) * __builtin_amdgcn_rcpf(mag + EPSF);
    er += __expf(scr * sc - mr);
    ei += __expf(sci * sc - mi);
  }
#pragma unroll
  for (int off = 1; off < 8; off <<= 1) {
    er += __shfl_xor(er, off);
    ei += __shfl_xor(ei, off);
  }
  if (jl == 0)
    stats[(size_t)b * 512 + i] = make_float4(mr, 1.f / er, mi, 1.f / ei);
}

// ---------------- k_y: Y[b,k] = X[b] @ W[k] (complex), written to ws in
// B-fragment layout, bf16: per (b,k): 128 lines (part*64 + js*4 + os) x 64 lanes x 16B
__global__ __launch_bounds__(256) void k_y(
    const float* __restrict__ Xr, const float* __restrict__ Xi,
    const float* __restrict__ Wr, const float* __restrict__ Wi,
    u32x4* __restrict__ yfrag)
{
  __shared__ __align__(16) short WtR[64 * 72];     // [o][c] pad 72
  __shared__ __align__(16) short WtI[64 * 72];
  __shared__ __align__(16) short Yt[4][2][64 * 24]; // per-wave [o][jj] pad 24
  int bk = blockIdx.x;
  int b = bk / 5, k = bk % 5;
  int t = threadIdx.x;
  {
    int o = t & 63, cbase = (t >> 6) * 16;
    const float* wr = Wr + (size_t)k * 4096;
    const float* wi = Wi + (size_t)k * 4096;
#pragma unroll
    for (int cc = 0; cc < 16; cc += 2) {
      int c = cbase + cc;
      *(unsigned*)&WtR[o * 72 + c] = pkbf(wr[c * 64 + o], wr[(c + 1) * 64 + o]);
      *(unsigned*)&WtI[o * 72 + c] = pkbf(wi[c * 64 + o], wi[(c + 1) * 64 + o]);
    }
  }
  __syncthreads();
  int w = t >> 6, l = t & 63;
  int lane15 = l & 15, quad = l >> 4;
  short* ytR = &Yt[w][0][0];
  short* ytI = &Yt[w][1][0];
  for (int qq = 0; qq < 8; ++qq) {
    int q = w * 8 + qq;
    int j = q * 16 + lane15;
    const f32x4* pxr = (const f32x4*)(Xr + ((size_t)b * 512 + j) * 64 + quad * 8);
    const f32x4* pxi = (const f32x4*)(Xi + ((size_t)b * 512 + j) * 64 + quad * 8);
    f32x4 xr0 = pxr[0], xr1 = pxr[1], xr8 = pxr[8], xr9 = pxr[9];
    f32x4 xi0 = pxi[0], xi1 = pxi[1], xi8 = pxi[8], xi9 = pxi[9];
    short8 axr[2], axi[2];
    axr[0] = mk8(pkbf(xr0[0], xr0[1]), pkbf(xr0[2], xr0[3]), pkbf(xr1[0], xr1[1]), pkbf(xr1[2], xr1[3]));
    axr[1] = mk8(pkbf(xr8[0], xr8[1]), pkbf(xr8[2], xr8[3]), pkbf(xr9[0], xr9[1]), pkbf(xr9[2], xr9[3]));
    axi[0] = mk8(pkbf(xi0[0], xi0[1]), pkbf(xi0[2], xi0[3]), pkbf(xi1[0], xi1[1]), pkbf(xi1[2], xi1[3]));
    axi[1] = mk8(pkbf(xi8[0], xi8[1]), pkbf(xi8[2], xi8[3]), pkbf(xi9[0], xi9[1]), pkbf(xi9[2], xi9[3]));
    f32x4 aR1[4], aR2[4], aI[4];
#pragma unroll
    for (int os = 0; os < 4; ++os) {
      aR1[os] = f32x4{0.f, 0.f, 0.f, 0.f};
      aR2[os] = f32x4{0.f, 0.f, 0.f, 0.f};
      aI[os] = f32x4{0.f, 0.f, 0.f, 0.f};
    }
#pragma unroll
    for (int kc = 0; kc < 2; ++kc) {
#pragma unroll
      for (int os = 0; os < 4; ++os) {
        int widx = (os * 16 + lane15) * 72 + kc * 32 + quad * 8;
        short8 wrF = *(const short8*)&WtR[widx];
        short8 wiF = *(const short8*)&WtI[widx];
        aR1[os] = __builtin_amdgcn_mfma_f32_16x16x32_bf16(axr[kc], wrF, aR1[os], 0, 0, 0);
        aR2[os] = __builtin_amdgcn_mfma_f32_16x16x32_bf16(axi[kc], wiF, aR2[os], 0, 0, 0);
        aI[os]  = __builtin_amdgcn_mfma_f32_16x16x32_bf16(axr[kc], wiF, aI[os], 0, 0, 0);
        aI[os]  = __builtin_amdgcn_mfma_f32_16x16x32_bf16(axi[kc], wrF, aI[os], 0, 0, 0);
      }
    }
#pragma unroll
    for (int os = 0; os < 4; ++os) {
      f32x4 R = aR1[os] - aR2[os];
      f32x4 I = aI[os];
      int ya = (os * 16 + lane15) * 24 + quad * 4;
      *(u32x2*)&ytR[ya] = u32x2{pkbf(R[0], R[1]), pkbf(R[2], R[3])};
      *(u32x2*)&ytI[ya] = u32x2{pkbf(I[0], I[1]), pkbf(I[2], I[3])};
    }
#pragma unroll
    for (int part = 0; part < 2; ++part) {
      const short* yt = part ? ytI : ytR;
#pragma unroll
      for (int h = 0; h < 2; ++h) {
        short8 unit = *(const short8*)&yt[l * 24 + h * 8];
        size_t line = (((size_t)(b * 5 + k) * 2 + part) * 16 + (q >> 1)) * 4 + (l >> 4);
        size_t idx = line * 64 + ((q & 1) * 2 + h) * 16 + (l & 15);
        yfrag[idx] = __builtin_bit_cast(u32x4, unit);
      }
    }
  }
}

// ---------------- k_main v3: lap tile shared via LDS (global_load_lds, double-
// buffered, counted vmcnt). 4 waves split the o-dimension (16 cols each); A=lap*a
// fragments recomputed per wave from the shared LDS tile. XOR-swizzled 16B units
// (swizzle applied on the GLOBAL source address; LDS dest stays linear).
__global__ __launch_bounds__(256, 4) void k_main(
    const float* __restrict__ lapr, const float* __restrict__ lapi,
    const float4* __restrict__ s4, const float4* __restrict__ stats,
    const float2* __restrict__ sj2, const u32x4* __restrict__ yfrag,
    const float* __restrict__ bar, const float* __restrict__ bai,
    const float* __restrict__ modbp,
    float* __restrict__ out_r, float* __restrict__ out_i)
{
  // 2 buffers x [kp=10][row=16][8 units of 16B] = 2 x 20KB = 40960 B exactly
  __shared__ __align__(16) unsigned char ldsb[40960];

  const int g = blockIdx.x;
  const int b = (g & 7) + ((g >> 8) << 3);   // XCD swizzle (1536 = 8*192, bijective)
  const int it = (g >> 3) & 31;
  const int t = threadIdx.x;
  const int w = t >> 6;                      // wave = o-slice 0..3
  const int l = t & 63;
  const int lane15 = l & 15, quad = l >> 4;
  const int gi = it * 16 + lane15;

  // ---- staging geometry: slot = w*5+q in 0..19 -> (kp = slot>>1, half = slot&1)
  // LDS dest (linear): slot*1024 + lane*16  ->  row = half*8 + (l>>3), stored unit = l&7
  // source unit = stored ^ (row&7)  (involution; read side applies the same XOR)
  const int srow = l >> 3;                   // row within half, == row&7
  const int sunit = (l & 7) ^ srow;          // swizzled source 16B unit
  const size_t NN = (size_t)512 * 512;
  const float* lapP0 = lapr + ((size_t)b * 5 * 512 + it * 16) * 512;
  const float* lapP1 = lapi + ((size_t)b * 5 * 512 + it * 16) * 512;
  const int slotbase = w * 5;
  const float* sptr[5];
#pragma unroll
  for (int q = 0; q < 5; ++q) {
    int slot = slotbase + q;
    int kp = slot >> 1, half = slot & 1;
    int k = kp >> 1, part = kp & 1;
    int row = half * 8 + srow;
    const float* base = part ? lapP1 : lapP0;
    sptr[q] = base + (size_t)k * NN + (size_t)row * 512 + sunit * 4;
  }

  float ba_r = bar[0], ba_i = bai[0], modb = modbp[0];
  float4 sv = s4[(size_t)b * 512 + gi];
  float4 st = stats[(size_t)b * 512 + gi];
  float sirb = sv.x + ba_r, siib = sv.y + ba_i;
  float maxr = st.x, rsr = st.y, maxi = st.z, rsi = st.w;

  f32x4 accR1 = {0.f, 0.f, 0.f, 0.f};
  f32x4 accR2 = {0.f, 0.f, 0.f, 0.f};
  f32x4 accI  = {0.f, 0.f, 0.f, 0.f};

  // prologue: stage js=0 into buffer 0
#pragma unroll
  for (int q = 0; q < 5; ++q)
    __builtin_amdgcn_global_load_lds(
        (const __attribute__((address_space(1))) unsigned int*)(sptr[q]),
        (__attribute__((address_space(3))) unsigned int*)(ldsb + (slotbase + q) * 1024),
        16, 0, 0);

  for (int js = 0; js < 16; ++js) {
    // current-js small loads FIRST (so vmcnt(5) below covers them)
    float2 sj[8];
#pragma unroll
    for (int e = 0; e < 8; ++e)
      sj[e] = sj2[(size_t)b * 512 + js * 32 + quad * 8 + e];
    u32x4 bRf[5], bIf[5];
#pragma unroll
    for (int k = 0; k < 5; ++k) {
      const u32x4* yk = yfrag + (size_t)(b * 5 + k) * 8192 + (size_t)(js * 4 + w) * 64 + l;
      bRf[k] = yk[0];
      bIf[k] = yk[4096];
    }
    // prefetch next js tile into the other buffer (stays in flight across barrier)
    if (js < 15) {
      unsigned bn = (unsigned)(((js + 1) & 1) * 20480);
#pragma unroll
      for (int q = 0; q < 5; ++q) {
        sptr[q] += 32;
        __builtin_amdgcn_global_load_lds(
            (const __attribute__((address_space(1))) unsigned int*)(sptr[q]),
            (__attribute__((address_space(3))) unsigned int*)(ldsb + bn + (slotbase + q) * 1024),
            16, 0, 0);
      }
    }
    // recompute attention weights a(i,j) for this lane's row x 8 j's
    float ar[8], ai[8];
#pragma unroll
    for (int e = 0; e < 8; ++e) {
      float scr = sirb + sj[e].x;
      float sci = siib + sj[e].y;
      float mag = sqrtf(scr * scr + sci * sci);
      float sc = fmaxf(mag + modb, 0.f) * __builtin_amdgcn_rcpf(mag + EPSF);
      ar[e] = __expf(scr * sc - maxr) * rsr;
      ai[e] = __expf(sci * sc - maxi) * rsi;
    }
    // wait current tile (+ sj + B) complete; leave the 5 prefetch loads in flight
    if (js < 15) asm volatile("s_waitcnt vmcnt(5)" ::: "memory");
    else         asm volatile("s_waitcnt vmcnt(0)" ::: "memory");
    __builtin_amdgcn_s_barrier();
    __builtin_amdgcn_sched_barrier(0);

    const unsigned char* buf = ldsb + (js & 1) * 20480;
    const int u0 = quad * 2;
    const int x7 = l & 7;
#pragma unroll
    for (int k = 0; k < 5; ++k) {
      f32x4 LR0 = *(const f32x4*)(buf + (k * 2 + 0) * 2048 + lane15 * 128 + (((u0    ) ^ x7) << 4));
      f32x4 LR1 = *(const f32x4*)(buf + (k * 2 + 0) * 2048 + lane15 * 128 + (((u0 + 1) ^ x7) << 4));
      f32x4 LI0 = *(const f32x4*)(buf + (k * 2 + 1) * 2048 + lane15 * 128 + (((u0    ) ^ x7) << 4));
      f32x4 LI1 = *(const f32x4*)(buf + (k * 2 + 1) * 2048 + lane15 * 128 + (((u0 + 1) ^ x7) << 4));
      float lrv[8], liv[8];
#pragma unroll
      for (int e = 0; e < 4; ++e) {
        lrv[e]     = LR0[e] * ar[e]     - LI0[e] * ai[e];
        liv[e]     = LR0[e] * ai[e]     + LI0[e] * ar[e];
        lrv[4 + e] = LR1[e] * ar[4 + e] - LI1[e] * ai[4 + e];
        liv[4 + e] = LR1[e] * ai[4 + e] + LI1[e] * ar[4 + e];
      }
      short8 Ar = mk8(pkbf(lrv[0], lrv[1]), pkbf(lrv[2], lrv[3]), pkbf(lrv[4], lrv[5]), pkbf(lrv[6], lrv[7]));
      short8 Ai = mk8(pkbf(liv[0], liv[1]), pkbf(liv[2], liv[3]), pkbf(liv[4], liv[5]), pkbf(liv[6], liv[7]));
      short8 br8 = __builtin_bit_cast(short8, bRf[k]);
      short8 bi8 = __builtin_bit_cast(short8, bIf[k]);
      accR1 = __builtin_amdgcn_mfma_f32_16x16x32_bf16(Ar, br8, accR1, 0, 0, 0);
      accR2 = __builtin_amdgcn_mfma_f32_16x16x32_bf16(Ai, bi8, accR2, 0, 0, 0);
      accI  = __builtin_amdgcn_mfma_f32_16x16x32_bf16(Ar, bi8, accI, 0, 0, 0);
      accI  = __builtin_amdgcn_mfma_f32_16x16x32_bf16(Ai, br8, accI, 0, 0, 0);
    }
    __builtin_amdgcn_sched_barrier(0);
    __builtin_amdgcn_s_barrier();   // all reads of this buffer done before re-staging
  }

  f32x4 R = accR1 - accR2;
  int oc = w * 16 + lane15;
#pragma unroll
  for (int r = 0; r < 4; ++r) {
    size_t oidx = ((size_t)b * 512 + it * 16 + quad * 4 + r) * 64 + oc;
    out_r[oidx] = R[r];
    out_i[oidx] = accI[r];
  }
}

extern "C" void kernel_launch(void* const* d_in, const int* in_sizes, int n_in,
                              void* d_out, int out_size, void* d_ws, size_t ws_size,
                              hipStream_t stream) {
  const float* Xr = (const float*)d_in[0];
  const float* Xi = (const float*)d_in[1];
  const float* lapr = (const float*)d_in[2];
  const float* lapi = (const float*)d_in[3];
  const float* War = (const float*)d_in[4];
  const float* Wai = (const float*)d_in[5];
  const float* bar = (const float*)d_in[6];
  const float* bai = (const float*)d_in[7];
  const float* modb = (const float*)d_in[8];
  const float* Wr = (const float*)d_in[9];
  const float* Wi = (const float*)d_in[10];

  // ws layout: s4 384KB | stats 384KB | sj2 192KB | yfrag 30MB  (total ~31.7MB)
  char* wsb = (char*)d_ws;
  float4* s4 = (float4*)wsb;
  float4* stats = (float4*)(wsb + 393216);
  float2* sj2 = (float2*)(wsb + 786432);
  u32x4* yfrag = (u32x4*)(wsb + 983040);

  float* out_r = (float*)d_out;
  float* out_i = out_r + (size_t)48 * 512 * 64;

  k_s<<<768, 256, 0, stream>>>(Xr, Xi, War, Wai, s4, sj2);
  k_stats<<<768, 256, 0, stream>>>(s4, sj2, bar, bai, modb, stats);
  k_y<<<240, 256, 0, stream>>>(Xr, Xi, Wr, Wi, yfrag);
  k_main<<<1536, 256, 0, stream>>>(lapr, lapi, s4, stats, sj2, yfrag,
                                   bar, bai, modb, out_r, out_i);
}

// Round 5
// 212.397 us; speedup vs baseline: 2.4847x; 1.1264x over previous
//
#include <hip/hip_runtime.h>

#define EPSF 1e-9f

typedef __attribute__((ext_vector_type(8))) short short8;
typedef __attribute__((ext_vector_type(4))) float f32x4;
typedef __attribute__((ext_vector_type(4))) unsigned int u32x4;
typedef __attribute__((ext_vector_type(2))) unsigned int u32x2;

__device__ __forceinline__ unsigned pkbf(float lo, float hi) {
  unsigned r;
  asm("v_cvt_pk_bf16_f32 %0, %1, %2" : "=v"(r) : "v"(lo), "v"(hi));
  return r;
}
__device__ __forceinline__ short8 mk8(unsigned a, unsigned b, unsigned c, unsigned d) {
  u32x4 u = {a, b, c, d};
  return __builtin_bit_cast(short8, u);
}

// ---------------- k_s: s[b,n] = (si_r, si_i, sj_r, sj_i); 8 lanes per row
__global__ __launch_bounds__(256) void k_s(
    const float* __restrict__ Xr, const float* __restrict__ Xi,
    const float* __restrict__ War, const float* __restrict__ Wai,
    float4* __restrict__ s4, float2* __restrict__ sj2)
{
  int t = threadIdx.x;
  int nf = blockIdx.x * 32 + (t >> 3);   // flat b*512+n
  int c0 = (t & 7) * 8;
  const f32x4* xr = (const f32x4*)(Xr + (size_t)nf * 64 + c0);
  const f32x4* xi = (const f32x4*)(Xi + (size_t)nf * 64 + c0);
  const f32x4* w1r = (const f32x4*)(War + c0);
  const f32x4* w2r = (const f32x4*)(War + 64 + c0);
  const f32x4* w1i = (const f32x4*)(Wai + c0);
  const f32x4* w2i = (const f32x4*)(Wai + 64 + c0);
  float sir = 0.f, sii = 0.f, sjr = 0.f, sji = 0.f;
#pragma unroll
  for (int h = 0; h < 2; ++h) {
    f32x4 a = xr[h], bb = xi[h];
    f32x4 u1r = w1r[h], u1i = w1i[h], u2r = w2r[h], u2i = w2i[h];
#pragma unroll
    for (int e = 0; e < 4; ++e) {
      sir += a[e] * u1r[e] - bb[e] * u1i[e];
      sii += a[e] * u1i[e] + bb[e] * u1r[e];
      sjr += a[e] * u2r[e] - bb[e] * u2i[e];
      sji += a[e] * u2i[e] + bb[e] * u2r[e];
    }
  }
#pragma unroll
  for (int off = 1; off < 8; off <<= 1) {
    sir += __shfl_xor(sir, off);
    sii += __shfl_xor(sii, off);
    sjr += __shfl_xor(sjr, off);
    sji += __shfl_xor(sji, off);
  }
  if ((t & 7) == 0) {
    s4[nf] = make_float4(sir, sii, sjr, sji);
    sj2[nf] = make_float2(sjr, sji);
  }
}

// ---------------- k_stats: per-(b,i) (max_r, 1/sum_r, max_i, 1/sum_i)
__global__ __launch_bounds__(256) void k_stats(
    const float4* __restrict__ s4, const float2* __restrict__ sj2,
    const float* __restrict__ bar, const float* __restrict__ bai,
    const float* __restrict__ modbp, float4* __restrict__ stats)
{
  __shared__ float2 sh[512];
  int t = threadIdx.x;
  int b = blockIdx.x >> 4;
  int i0 = (blockIdx.x & 15) * 32;
  sh[t] = sj2[(size_t)b * 512 + t];
  sh[t + 256] = sj2[(size_t)b * 512 + t + 256];
  __syncthreads();
  float ba_r = bar[0], ba_i = bai[0], modb = modbp[0];
  int i = i0 + (t >> 3), jl = t & 7;
  float4 sv = s4[(size_t)b * 512 + i];
  float sirb = sv.x + ba_r, siib = sv.y + ba_i;
  float mr = -1e30f, mi = -1e30f;
  for (int jj = 0; jj < 64; ++jj) {
    float2 sj = sh[jl * 64 + jj];
    float scr = sirb + sj.x, sci = siib + sj.y;
    float mag = sqrtf(scr * scr + sci * sci);
    float sc = fmaxf(mag + modb, 0.f) * __builtin_amdgcn_rcpf(mag + EPSF);
    mr = fmaxf(mr, scr * sc);
    mi = fmaxf(mi, sci * sc);
  }
#pragma unroll
  for (int off = 1; off < 8; off <<= 1) {
    mr = fmaxf(mr, __shfl_xor(mr, off));
    mi = fmaxf(mi, __shfl_xor(mi, off));
  }
  float er = 0.f, ei = 0.f;
  for (int jj = 0; jj < 64; ++jj) {
    float2 sj = sh[jl * 64 + jj];
    float scr = sirb + sj.x, sci = siib + sj.y;
    float mag = sqrtf(scr * scr + sci * sci);
    float sc = fmaxf(mag + modb, 0.f) * __builtin_amdgcn_rcpf(mag + EPSF);
    er += __expf(scr * sc - mr);
    ei += __expf(sci * sc - mi);
  }
#pragma unroll
  for (int off = 1; off < 8; off <<= 1) {
    er += __shfl_xor(er, off);
    ei += __shfl_xor(ei, off);
  }
  if (jl == 0)
    stats[(size_t)b * 512 + i] = make_float4(mr, 1.f / er, mi, 1.f / ei);
}

// ---------------- k_y: Y[b,k] = X[b] @ W[k] (complex), written to ws in
// B-fragment layout, bf16: per (b,k): 128 lines (part*64 + js*4 + os) x 64 lanes x 16B
__global__ __launch_bounds__(256) void k_y(
    const float* __restrict__ Xr, const float* __restrict__ Xi,
    const float* __restrict__ Wr, const float* __restrict__ Wi,
    u32x4* __restrict__ yfrag)
{
  __shared__ __align__(16) short WtR[64 * 72];     // [o][c] pad 72
  __shared__ __align__(16) short WtI[64 * 72];
  __shared__ __align__(16) short Yt[4][2][64 * 24]; // per-wave [o][jj] pad 24
  int bk = blockIdx.x;
  int b = bk / 5, k = bk % 5;
  int t = threadIdx.x;
  {
    int o = t & 63, cbase = (t >> 6) * 16;
    const float* wr = Wr + (size_t)k * 4096;
    const float* wi = Wi + (size_t)k * 4096;
#pragma unroll
    for (int cc = 0; cc < 16; cc += 2) {
      int c = cbase + cc;
      *(unsigned*)&WtR[o * 72 + c] = pkbf(wr[c * 64 + o], wr[(c + 1) * 64 + o]);
      *(unsigned*)&WtI[o * 72 + c] = pkbf(wi[c * 64 + o], wi[(c + 1) * 64 + o]);
    }
  }
  __syncthreads();
  int w = t >> 6, l = t & 63;
  int lane15 = l & 15, quad = l >> 4;
  short* ytR = &Yt[w][0][0];
  short* ytI = &Yt[w][1][0];
  for (int qq = 0; qq < 8; ++qq) {
    int q = w * 8 + qq;
    int j = q * 16 + lane15;
    const f32x4* pxr = (const f32x4*)(Xr + ((size_t)b * 512 + j) * 64 + quad * 8);
    const f32x4* pxi = (const f32x4*)(Xi + ((size_t)b * 512 + j) * 64 + quad * 8);
    f32x4 xr0 = pxr[0], xr1 = pxr[1], xr8 = pxr[8], xr9 = pxr[9];
    f32x4 xi0 = pxi[0], xi1 = pxi[1], xi8 = pxi[8], xi9 = pxi[9];
    short8 axr[2], axi[2];
    axr[0] = mk8(pkbf(xr0[0], xr0[1]), pkbf(xr0[2], xr0[3]), pkbf(xr1[0], xr1[1]), pkbf(xr1[2], xr1[3]));
    axr[1] = mk8(pkbf(xr8[0], xr8[1]), pkbf(xr8[2], xr8[3]), pkbf(xr9[0], xr9[1]), pkbf(xr9[2], xr9[3]));
    axi[0] = mk8(pkbf(xi0[0], xi0[1]), pkbf(xi0[2], xi0[3]), pkbf(xi1[0], xi1[1]), pkbf(xi1[2], xi1[3]));
    axi[1] = mk8(pkbf(xi8[0], xi8[1]), pkbf(xi8[2], xi8[3]), pkbf(xi9[0], xi9[1]), pkbf(xi9[2], xi9[3]));
    f32x4 aR1[4], aR2[4], aI[4];
#pragma unroll
    for (int os = 0; os < 4; ++os) {
      aR1[os] = f32x4{0.f, 0.f, 0.f, 0.f};
      aR2[os] = f32x4{0.f, 0.f, 0.f, 0.f};
      aI[os] = f32x4{0.f, 0.f, 0.f, 0.f};
    }
#pragma unroll
    for (int kc = 0; kc < 2; ++kc) {
#pragma unroll
      for (int os = 0; os < 4; ++os) {
        int widx = (os * 16 + lane15) * 72 + kc * 32 + quad * 8;
        short8 wrF = *(const short8*)&WtR[widx];
        short8 wiF = *(const short8*)&WtI[widx];
        aR1[os] = __builtin_amdgcn_mfma_f32_16x16x32_bf16(axr[kc], wrF, aR1[os], 0, 0, 0);
        aR2[os] = __builtin_amdgcn_mfma_f32_16x16x32_bf16(axi[kc], wiF, aR2[os], 0, 0, 0);
        aI[os]  = __builtin_amdgcn_mfma_f32_16x16x32_bf16(axr[kc], wiF, aI[os], 0, 0, 0);
        aI[os]  = __builtin_amdgcn_mfma_f32_16x16x32_bf16(axi[kc], wrF, aI[os], 0, 0, 0);
      }
    }
#pragma unroll
    for (int os = 0; os < 4; ++os) {
      f32x4 R = aR1[os] - aR2[os];
      f32x4 I = aI[os];
      int ya = (os * 16 + lane15) * 24 + quad * 4;
      *(u32x2*)&ytR[ya] = u32x2{pkbf(R[0], R[1]), pkbf(R[2], R[3])};
      *(u32x2*)&ytI[ya] = u32x2{pkbf(I[0], I[1]), pkbf(I[2], I[3])};
    }
#pragma unroll
    for (int part = 0; part < 2; ++part) {
      const short* yt = part ? ytI : ytR;
#pragma unroll
      for (int h = 0; h < 2; ++h) {
        short8 unit = *(const short8*)&yt[l * 24 + h * 8];
        size_t line = (((size_t)(b * 5 + k) * 2 + part) * 16 + (q >> 1)) * 4 + (l >> 4);
        size_t idx = line * 64 + ((q & 1) * 2 + h) * 16 + (l & 15);
        yfrag[idx] = __builtin_bit_cast(u32x4, unit);
      }
    }
  }
}

// ---------------- k_main v4: j-split across 4 waves (each wave owns 4 of 16
// js-steps -> every (i,j) A-fragment formed exactly once). lap loads go
// register-direct (no LDS staging, no barriers in main loop). Per js-step:
// phase 1 packs all 5k A-fragments (Ar, Ai) in bf16; phase 2 is pure
// B-load + MFMA with a sign-negated Ai (xor 0x80008000) so real part needs
// one accumulator. Cross-wave tree-reduce through 16 KB LDS at the end.
__global__ __launch_bounds__(256, 4) void k_main(
    const float* __restrict__ lapr, const float* __restrict__ lapi,
    const float4* __restrict__ s4, const float4* __restrict__ stats,
    const float2* __restrict__ sj2, const u32x4* __restrict__ yfrag,
    const float* __restrict__ bar, const float* __restrict__ bai,
    const float* __restrict__ modbp,
    float* __restrict__ out_r, float* __restrict__ out_i)
{
  __shared__ __align__(16) f32x4 red[2][64][8];   // 16 KB tree-reduce buffer

  const int g = blockIdx.x;
  const int b = (g & 7) + ((g >> 8) << 3);   // XCD swizzle (1536 = 8*192, bijective)
  const int it = (g >> 3) & 31;
  const int t = threadIdx.x;
  const int w = t >> 6;                      // wave = js-slice 0..3
  const int l = t & 63;
  const int lane15 = l & 15, quad = l >> 4;
  const int gi = it * 16 + lane15;

  float ba_r = bar[0], ba_i = bai[0], modb = modbp[0];
  float4 sv = s4[(size_t)b * 512 + gi];
  float4 st = stats[(size_t)b * 512 + gi];
  float sirb = sv.x + ba_r, siib = sv.y + ba_i;
  float maxr = st.x, rsr = st.y, maxi = st.z, rsi = st.w;

  f32x4 accR[4], accI[4];
#pragma unroll
  for (int os = 0; os < 4; ++os) {
    accR[os] = f32x4{0.f, 0.f, 0.f, 0.f};
    accI[os] = f32x4{0.f, 0.f, 0.f, 0.f};
  }

  const size_t NN = (size_t)512 * 512;
  const float* lapr_b = lapr + ((size_t)b * 5 * 512 + gi) * 512;
  const float* lapi_b = lapi + ((size_t)b * 5 * 512 + gi) * 512;
  const u32x4* yb = yfrag + (size_t)b * 5 * 8192 + l;

  for (int jsw = 0; jsw < 4; ++jsw) {
    const int js = w * 4 + jsw;
    const int jq = js * 32 + quad * 8;

    // sj pairs for this lane's 8 j's (vectorized: 4x f32x4 = 8 float2)
    const f32x4* sjp = (const f32x4*)(sj2 + (size_t)b * 512 + jq);
    f32x4 sjv0 = sjp[0], sjv1 = sjp[1], sjv2 = sjp[2], sjv3 = sjp[3];
    float sjr[8] = {sjv0[0], sjv0[2], sjv1[0], sjv1[2], sjv2[0], sjv2[2], sjv3[0], sjv3[2]};
    float sjimag[8] = {sjv0[1], sjv0[3], sjv1[1], sjv1[3], sjv2[1], sjv2[3], sjv3[1], sjv3[3]};

    // attention weights a(i,j) — each (i,j) computed by exactly one lane
    float ar[8], ai[8];
#pragma unroll
    for (int e = 0; e < 8; ++e) {
      float scr = sirb + sjr[e];
      float sci = siib + sjimag[e];
      float mag = __builtin_amdgcn_sqrtf(fmaf(scr, scr, sci * sci));
      float sc = fmaxf(mag + modb, 0.f) * __builtin_amdgcn_rcpf(mag + EPSF);
      ar[e] = __expf(fmaf(scr, sc, -maxr)) * rsr;
      ai[e] = __expf(fmaf(sci, sc, -maxi)) * rsi;
    }

    // phase 1: load lap per-k, form packed A-fragments (lap regs transient)
    unsigned pAr[5][4], pAi[5][4];
#pragma unroll
    for (int k = 0; k < 5; ++k) {
      const f32x4* pr = (const f32x4*)(lapr_b + (size_t)k * NN + jq);
      const f32x4* pi_ = (const f32x4*)(lapi_b + (size_t)k * NN + jq);
      f32x4 LR0 = __builtin_nontemporal_load(pr);
      f32x4 LR1 = __builtin_nontemporal_load(pr + 1);
      f32x4 LI0 = __builtin_nontemporal_load(pi_);
      f32x4 LI1 = __builtin_nontemporal_load(pi_ + 1);
      float lrv[8], liv[8];
#pragma unroll
      for (int e = 0; e < 4; ++e) {
        lrv[e]     = LR0[e] * ar[e]     - LI0[e] * ai[e];
        liv[e]     = LR0[e] * ai[e]     + LI0[e] * ar[e];
        lrv[4 + e] = LR1[e] * ar[4 + e] - LI1[e] * ai[4 + e];
        liv[4 + e] = LR1[e] * ai[4 + e] + LI1[e] * ar[4 + e];
      }
      pAr[k][0] = pkbf(lrv[0], lrv[1]); pAr[k][1] = pkbf(lrv[2], lrv[3]);
      pAr[k][2] = pkbf(lrv[4], lrv[5]); pAr[k][3] = pkbf(lrv[6], lrv[7]);
      pAi[k][0] = pkbf(liv[0], liv[1]); pAi[k][1] = pkbf(liv[2], liv[3]);
      pAi[k][2] = pkbf(liv[4], liv[5]); pAi[k][3] = pkbf(liv[6], liv[7]);
    }

    // phase 2: pure B-load + MFMA
#pragma unroll
    for (int k = 0; k < 5; ++k) {
      const u32x4* yk = yb + (size_t)k * 8192 + (size_t)(js * 4) * 64;
      short8 Ar = mk8(pAr[k][0], pAr[k][1], pAr[k][2], pAr[k][3]);
      short8 Ai = mk8(pAi[k][0], pAi[k][1], pAi[k][2], pAi[k][3]);
      short8 An = mk8(pAi[k][0] ^ 0x80008000u, pAi[k][1] ^ 0x80008000u,
                      pAi[k][2] ^ 0x80008000u, pAi[k][3] ^ 0x80008000u);
#pragma unroll
      for (int os = 0; os < 4; ++os) {
        short8 br8 = __builtin_bit_cast(short8, yk[os * 64]);
        short8 bi8 = __builtin_bit_cast(short8, yk[4096 + os * 64]);
        accR[os] = __builtin_amdgcn_mfma_f32_16x16x32_bf16(Ar, br8, accR[os], 0, 0, 0);
        accR[os] = __builtin_amdgcn_mfma_f32_16x16x32_bf16(An, bi8, accR[os], 0, 0, 0);
        accI[os] = __builtin_amdgcn_mfma_f32_16x16x32_bf16(Ar, bi8, accI[os], 0, 0, 0);
        accI[os] = __builtin_amdgcn_mfma_f32_16x16x32_bf16(Ai, br8, accI[os], 0, 0, 0);
      }
    }
  }

  // ---- tree-reduce partial sums across the 4 waves
  if (w >= 2) {
#pragma unroll
    for (int os = 0; os < 4; ++os) {
      red[w - 2][l][os] = accR[os];
      red[w - 2][l][4 + os] = accI[os];
    }
  }
  __syncthreads();
  if (w < 2) {
#pragma unroll
    for (int os = 0; os < 4; ++os) {
      accR[os] += red[w][l][os];
      accI[os] += red[w][l][4 + os];
    }
  }
  __syncthreads();
  if (w == 1) {
#pragma unroll
    for (int os = 0; os < 4; ++os) {
      red[0][l][os] = accR[os];
      red[0][l][4 + os] = accI[os];
    }
  }
  __syncthreads();
  if (w == 0) {
#pragma unroll
    for (int os = 0; os < 4; ++os) {
      accR[os] += red[0][l][os];
      accI[os] += red[0][l][4 + os];
      int oc = os * 16 + lane15;
#pragma unroll
      for (int r = 0; r < 4; ++r) {
        size_t oidx = ((size_t)b * 512 + it * 16 + quad * 4 + r) * 64 + oc;
        out_r[oidx] = accR[os][r];
        out_i[oidx] = accI[os][r];
      }
    }
  }
}

extern "C" void kernel_launch(void* const* d_in, const int* in_sizes, int n_in,
                              void* d_out, int out_size, void* d_ws, size_t ws_size,
                              hipStream_t stream) {
  const float* Xr = (const float*)d_in[0];
  const float* Xi = (const float*)d_in[1];
  const float* lapr = (const float*)d_in[2];
  const float* lapi = (const float*)d_in[3];
  const float* War = (const float*)d_in[4];
  const float* Wai = (const float*)d_in[5];
  const float* bar = (const float*)d_in[6];
  const float* bai = (const float*)d_in[7];
  const float* modb = (const float*)d_in[8];
  const float* Wr = (const float*)d_in[9];
  const float* Wi = (const float*)d_in[10];

  // ws layout: s4 384KB | stats 384KB | sj2 192KB | yfrag 30MB  (total ~31.7MB)
  char* wsb = (char*)d_ws;
  float4* s4 = (float4*)wsb;
  float4* stats = (float4*)(wsb + 393216);
  float2* sj2 = (float2*)(wsb + 786432);
  u32x4* yfrag = (u32x4*)(wsb + 983040);

  float* out_r = (float*)d_out;
  float* out_i = out_r + (size_t)48 * 512 * 64;

  k_s<<<768, 256, 0, stream>>>(Xr, Xi, War, Wai, s4, sj2);
  k_stats<<<768, 256, 0, stream>>>(s4, sj2, bar, bai, modb, stats);
  k_y<<<240, 256, 0, stream>>>(Xr, Xi, Wr, Wi, yfrag);
  k_main<<<1536, 256, 0, stream>>>(lapr, lapi, s4, stats, sj2, yfrag,
                                   bar, bai, modb, out_r, out_i);
}

// Round 6
// 199.338 us; speedup vs baseline: 2.6475x; 1.0655x over previous
//
#include <hip/hip_runtime.h>

#define EPSF 1e-9f

typedef __attribute__((ext_vector_type(8))) short short8;
typedef __attribute__((ext_vector_type(4))) float f32x4;
typedef __attribute__((ext_vector_type(4))) unsigned int u32x4;
typedef __attribute__((ext_vector_type(2))) unsigned int u32x2;

__device__ __forceinline__ unsigned pkbf(float lo, float hi) {
  unsigned r;
  asm("v_cvt_pk_bf16_f32 %0, %1, %2" : "=v"(r) : "v"(lo), "v"(hi));
  return r;
}
__device__ __forceinline__ short8 mk8(unsigned a, unsigned b, unsigned c, unsigned d) {
  u32x4 u = {a, b, c, d};
  return __builtin_bit_cast(short8, u);
}

// ---------------- k_s: s[b,n] = (si_r, si_i, sj_r, sj_i); 8 lanes per row
__global__ __launch_bounds__(256) void k_s(
    const float* __restrict__ Xr, const float* __restrict__ Xi,
    const float* __restrict__ War, const float* __restrict__ Wai,
    float4* __restrict__ s4, float2* __restrict__ sj2)
{
  int t = threadIdx.x;
  int nf = blockIdx.x * 32 + (t >> 3);   // flat b*512+n
  int c0 = (t & 7) * 8;
  const f32x4* xr = (const f32x4*)(Xr + (size_t)nf * 64 + c0);
  const f32x4* xi = (const f32x4*)(Xi + (size_t)nf * 64 + c0);
  const f32x4* w1r = (const f32x4*)(War + c0);
  const f32x4* w2r = (const f32x4*)(War + 64 + c0);
  const f32x4* w1i = (const f32x4*)(Wai + c0);
  const f32x4* w2i = (const f32x4*)(Wai + 64 + c0);
  float sir = 0.f, sii = 0.f, sjr = 0.f, sji = 0.f;
#pragma unroll
  for (int h = 0; h < 2; ++h) {
    f32x4 a = xr[h], bb = xi[h];
    f32x4 u1r = w1r[h], u1i = w1i[h], u2r = w2r[h], u2i = w2i[h];
#pragma unroll
    for (int e = 0; e < 4; ++e) {
      sir += a[e] * u1r[e] - bb[e] * u1i[e];
      sii += a[e] * u1i[e] + bb[e] * u1r[e];
      sjr += a[e] * u2r[e] - bb[e] * u2i[e];
      sji += a[e] * u2i[e] + bb[e] * u2r[e];
    }
  }
#pragma unroll
  for (int off = 1; off < 8; off <<= 1) {
    sir += __shfl_xor(sir, off);
    sii += __shfl_xor(sii, off);
    sjr += __shfl_xor(sjr, off);
    sji += __shfl_xor(sji, off);
  }
  if ((t & 7) == 0) {
    s4[nf] = make_float4(sir, sii, sjr, sji);
    sj2[nf] = make_float2(sjr, sji);
  }
}

// ---------------- k_stats: per-(b,i) (max_r, 1/sum_r, max_i, 1/sum_i)
__global__ __launch_bounds__(256) void k_stats(
    const float4* __restrict__ s4, const float2* __restrict__ sj2,
    const float* __restrict__ bar, const float* __restrict__ bai,
    const float* __restrict__ modbp, float4* __restrict__ stats)
{
  __shared__ float2 sh[512];
  int t = threadIdx.x;
  int b = blockIdx.x >> 4;
  int i0 = (blockIdx.x & 15) * 32;
  sh[t] = sj2[(size_t)b * 512 + t];
  sh[t + 256] = sj2[(size_t)b * 512 + t + 256];
  __syncthreads();
  float ba_r = bar[0], ba_i = bai[0], modb = modbp[0];
  int i = i0 + (t >> 3), jl = t & 7;
  float4 sv = s4[(size_t)b * 512 + i];
  float sirb = sv.x + ba_r, siib = sv.y + ba_i;
  float mr = -1e30f, mi = -1e30f;
  for (int jj = 0; jj < 64; ++jj) {
    float2 sj = sh[jl * 64 + jj];
    float scr = sirb + sj.x, sci = siib + sj.y;
    float mag = sqrtf(scr * scr + sci * sci);
    float sc = fmaxf(mag + modb, 0.f) * __builtin_amdgcn_rcpf(mag + EPSF);
    mr = fmaxf(mr, scr * sc);
    mi = fmaxf(mi, sci * sc);
  }
#pragma unroll
  for (int off = 1; off < 8; off <<= 1) {
    mr = fmaxf(mr, __shfl_xor(mr, off));
    mi = fmaxf(mi, __shfl_xor(mi, off));
  }
  float er = 0.f, ei = 0.f;
  for (int jj = 0; jj < 64; ++jj) {
    float2 sj = sh[jl * 64 + jj];
    float scr = sirb + sj.x, sci = siib + sj.y;
    float mag = sqrtf(scr * scr + sci * sci);
    float sc = fmaxf(mag + modb, 0.f) * __builtin_amdgcn_rcpf(mag + EPSF);
    er += __expf(scr * sc - mr);
    ei += __expf(sci * sc - mi);
  }
#pragma unroll
  for (int off = 1; off < 8; off <<= 1) {
    er += __shfl_xor(er, off);
    ei += __shfl_xor(ei, off);
  }
  if (jl == 0)
    stats[(size_t)b * 512 + i] = make_float4(mr, 1.f / er, mi, 1.f / ei);
}

// ---------------- k_y: Y[b,k] = X[b] @ W[k] (complex), written to ws in
// B-fragment layout, bf16: per (b,k): 128 lines (part*64 + js*4 + os) x 64 lanes x 16B
__global__ __launch_bounds__(256) void k_y(
    const float* __restrict__ Xr, const float* __restrict__ Xi,
    const float* __restrict__ Wr, const float* __restrict__ Wi,
    u32x4* __restrict__ yfrag)
{
  __shared__ __align__(16) short WtR[64 * 72];     // [o][c] pad 72
  __shared__ __align__(16) short WtI[64 * 72];
  __shared__ __align__(16) short Yt[4][2][64 * 24]; // per-wave [o][jj] pad 24
  int bk = blockIdx.x;
  int b = bk / 5, k = bk % 5;
  int t = threadIdx.x;
  {
    int o = t & 63, cbase = (t >> 6) * 16;
    const float* wr = Wr + (size_t)k * 4096;
    const float* wi = Wi + (size_t)k * 4096;
#pragma unroll
    for (int cc = 0; cc < 16; cc += 2) {
      int c = cbase + cc;
      *(unsigned*)&WtR[o * 72 + c] = pkbf(wr[c * 64 + o], wr[(c + 1) * 64 + o]);
      *(unsigned*)&WtI[o * 72 + c] = pkbf(wi[c * 64 + o], wi[(c + 1) * 64 + o]);
    }
  }
  __syncthreads();
  int w = t >> 6, l = t & 63;
  int lane15 = l & 15, quad = l >> 4;
  short* ytR = &Yt[w][0][0];
  short* ytI = &Yt[w][1][0];
  for (int qq = 0; qq < 8; ++qq) {
    int q = w * 8 + qq;
    int j = q * 16 + lane15;
    const f32x4* pxr = (const f32x4*)(Xr + ((size_t)b * 512 + j) * 64 + quad * 8);
    const f32x4* pxi = (const f32x4*)(Xi + ((size_t)b * 512 + j) * 64 + quad * 8);
    f32x4 xr0 = pxr[0], xr1 = pxr[1], xr8 = pxr[8], xr9 = pxr[9];
    f32x4 xi0 = pxi[0], xi1 = pxi[1], xi8 = pxi[8], xi9 = pxi[9];
    short8 axr[2], axi[2];
    axr[0] = mk8(pkbf(xr0[0], xr0[1]), pkbf(xr0[2], xr0[3]), pkbf(xr1[0], xr1[1]), pkbf(xr1[2], xr1[3]));
    axr[1] = mk8(pkbf(xr8[0], xr8[1]), pkbf(xr8[2], xr8[3]), pkbf(xr9[0], xr9[1]), pkbf(xr9[2], xr9[3]));
    axi[0] = mk8(pkbf(xi0[0], xi0[1]), pkbf(xi0[2], xi0[3]), pkbf(xi1[0], xi1[1]), pkbf(xi1[2], xi1[3]));
    axi[1] = mk8(pkbf(xi8[0], xi8[1]), pkbf(xi8[2], xi8[3]), pkbf(xi9[0], xi9[1]), pkbf(xi9[2], xi9[3]));
    f32x4 aR1[4], aR2[4], aI[4];
#pragma unroll
    for (int os = 0; os < 4; ++os) {
      aR1[os] = f32x4{0.f, 0.f, 0.f, 0.f};
      aR2[os] = f32x4{0.f, 0.f, 0.f, 0.f};
      aI[os] = f32x4{0.f, 0.f, 0.f, 0.f};
    }
#pragma unroll
    for (int kc = 0; kc < 2; ++kc) {
#pragma unroll
      for (int os = 0; os < 4; ++os) {
        int widx = (os * 16 + lane15) * 72 + kc * 32 + quad * 8;
        short8 wrF = *(const short8*)&WtR[widx];
        short8 wiF = *(const short8*)&WtI[widx];
        aR1[os] = __builtin_amdgcn_mfma_f32_16x16x32_bf16(axr[kc], wrF, aR1[os], 0, 0, 0);
        aR2[os] = __builtin_amdgcn_mfma_f32_16x16x32_bf16(axi[kc], wiF, aR2[os], 0, 0, 0);
        aI[os]  = __builtin_amdgcn_mfma_f32_16x16x32_bf16(axr[kc], wiF, aI[os], 0, 0, 0);
        aI[os]  = __builtin_amdgcn_mfma_f32_16x16x32_bf16(axi[kc], wrF, aI[os], 0, 0, 0);
      }
    }
#pragma unroll
    for (int os = 0; os < 4; ++os) {
      f32x4 R = aR1[os] - aR2[os];
      f32x4 I = aI[os];
      int ya = (os * 16 + lane15) * 24 + quad * 4;
      *(u32x2*)&ytR[ya] = u32x2{pkbf(R[0], R[1]), pkbf(R[2], R[3])};
      *(u32x2*)&ytI[ya] = u32x2{pkbf(I[0], I[1]), pkbf(I[2], I[3])};
    }
#pragma unroll
    for (int part = 0; part < 2; ++part) {
      const short* yt = part ? ytI : ytR;
#pragma unroll
      for (int h = 0; h < 2; ++h) {
        short8 unit = *(const short8*)&yt[l * 24 + h * 8];
        size_t line = (((size_t)(b * 5 + k) * 2 + part) * 16 + (q >> 1)) * 4 + (l >> 4);
        size_t idx = line * 64 + ((q & 1) * 2 + h) * 16 + (l & 15);
        yfrag[idx] = __builtin_bit_cast(u32x4, unit);
      }
    }
  }
}

// ---------------- k_main v5: j-split across 4 waves, register-direct lap loads.
// Per js-step: issue sj + ALL 20 lap loads into live registers (one exposed HBM
// round-trip), sched_barrier pins them above the lap-independent a-compute
// (which runs under the load latency), then per-k {pack A, load B, 16 MFMA}
// keeps pA/B lifetimes short. launch_bounds(256,3) -> VGPR cap ~168, no spill.
__global__ __launch_bounds__(256, 3) void k_main(
    const float* __restrict__ lapr, const float* __restrict__ lapi,
    const float4* __restrict__ s4, const float4* __restrict__ stats,
    const float2* __restrict__ sj2, const u32x4* __restrict__ yfrag,
    const float* __restrict__ bar, const float* __restrict__ bai,
    const float* __restrict__ modbp,
    float* __restrict__ out_r, float* __restrict__ out_i)
{
  __shared__ __align__(16) f32x4 red[2][64][8];   // 16 KB tree-reduce buffer

  const int g = blockIdx.x;
  const int b = (g & 7) + ((g >> 8) << 3);   // XCD swizzle (1536 = 8*192, bijective)
  const int it = (g >> 3) & 31;
  const int t = threadIdx.x;
  const int w = t >> 6;                      // wave = js-slice 0..3
  const int l = t & 63;
  const int lane15 = l & 15, quad = l >> 4;
  const int gi = it * 16 + lane15;

  float ba_r = bar[0], ba_i = bai[0], modb = modbp[0];
  float4 sv = s4[(size_t)b * 512 + gi];
  float4 st = stats[(size_t)b * 512 + gi];
  float sirb = sv.x + ba_r, siib = sv.y + ba_i;
  float maxr = st.x, rsr = st.y, maxi = st.z, rsi = st.w;

  f32x4 accR[4], accI[4];
#pragma unroll
  for (int os = 0; os < 4; ++os) {
    accR[os] = f32x4{0.f, 0.f, 0.f, 0.f};
    accI[os] = f32x4{0.f, 0.f, 0.f, 0.f};
  }

  const size_t NN = (size_t)512 * 512;
  const float* lapr_b = lapr + ((size_t)b * 5 * 512 + gi) * 512;
  const float* lapi_b = lapi + ((size_t)b * 5 * 512 + gi) * 512;
  const u32x4* yb = yfrag + (size_t)b * 5 * 8192 + l;

  for (int jsw = 0; jsw < 4; ++jsw) {
    const int js = w * 4 + jsw;
    const int jq = js * 32 + quad * 8;

    // --- issue sj loads, then ALL 20 lap loads (kept live together in VGPRs)
    const f32x4* sjp = (const f32x4*)(sj2 + (size_t)b * 512 + jq);
    f32x4 sjv0 = sjp[0], sjv1 = sjp[1], sjv2 = sjp[2], sjv3 = sjp[3];

    f32x4 LR[5][2], LI[5][2];
#pragma unroll
    for (int k = 0; k < 5; ++k) {
      const f32x4* pr = (const f32x4*)(lapr_b + (size_t)k * NN + jq);
      const f32x4* pi_ = (const f32x4*)(lapi_b + (size_t)k * NN + jq);
      LR[k][0] = __builtin_nontemporal_load(pr);
      LR[k][1] = __builtin_nontemporal_load(pr + 1);
      LI[k][0] = __builtin_nontemporal_load(pi_);
      LI[k][1] = __builtin_nontemporal_load(pi_ + 1);
    }
    __builtin_amdgcn_sched_barrier(0);   // pin load issue above the a-compute

    // --- a-compute: independent of lap loads, runs under their latency
    float sjr[8] = {sjv0[0], sjv0[2], sjv1[0], sjv1[2], sjv2[0], sjv2[2], sjv3[0], sjv3[2]};
    float sjimag[8] = {sjv0[1], sjv0[3], sjv1[1], sjv1[3], sjv2[1], sjv2[3], sjv3[1], sjv3[3]};
    float ar[8], ai[8];
#pragma unroll
    for (int e = 0; e < 8; ++e) {
      float scr = sirb + sjr[e];
      float sci = siib + sjimag[e];
      float mag = __builtin_amdgcn_sqrtf(fmaf(scr, scr, sci * sci));
      float sc = fmaxf(mag + modb, 0.f) * __builtin_amdgcn_rcpf(mag + EPSF);
      ar[e] = __expf(fmaf(scr, sc, -maxr)) * rsr;
      ai[e] = __expf(fmaf(sci, sc, -maxi)) * rsi;
    }

    // --- per k: pack A (short-lived), load B (L2), 16 MFMA
#pragma unroll
    for (int k = 0; k < 5; ++k) {
      float lrv[8], liv[8];
#pragma unroll
      for (int e = 0; e < 4; ++e) {
        lrv[e]     = LR[k][0][e] * ar[e]     - LI[k][0][e] * ai[e];
        liv[e]     = LR[k][0][e] * ai[e]     + LI[k][0][e] * ar[e];
        lrv[4 + e] = LR[k][1][e] * ar[4 + e] - LI[k][1][e] * ai[4 + e];
        liv[4 + e] = LR[k][1][e] * ai[4 + e] + LI[k][1][e] * ar[4 + e];
      }
      unsigned p0 = pkbf(lrv[0], lrv[1]), p1 = pkbf(lrv[2], lrv[3]);
      unsigned p2 = pkbf(lrv[4], lrv[5]), p3 = pkbf(lrv[6], lrv[7]);
      unsigned q0 = pkbf(liv[0], liv[1]), q1 = pkbf(liv[2], liv[3]);
      unsigned q2 = pkbf(liv[4], liv[5]), q3 = pkbf(liv[6], liv[7]);
      short8 Ar = mk8(p0, p1, p2, p3);
      short8 Ai = mk8(q0, q1, q2, q3);
      short8 An = mk8(q0 ^ 0x80008000u, q1 ^ 0x80008000u,
                      q2 ^ 0x80008000u, q3 ^ 0x80008000u);

      const u32x4* yk = yb + (size_t)k * 8192 + (size_t)(js * 4) * 64;
#pragma unroll
      for (int os = 0; os < 4; ++os) {
        short8 br8 = __builtin_bit_cast(short8, yk[os * 64]);
        short8 bi8 = __builtin_bit_cast(short8, yk[4096 + os * 64]);
        accR[os] = __builtin_amdgcn_mfma_f32_16x16x32_bf16(Ar, br8, accR[os], 0, 0, 0);
        accR[os] = __builtin_amdgcn_mfma_f32_16x16x32_bf16(An, bi8, accR[os], 0, 0, 0);
        accI[os] = __builtin_amdgcn_mfma_f32_16x16x32_bf16(Ar, bi8, accI[os], 0, 0, 0);
        accI[os] = __builtin_amdgcn_mfma_f32_16x16x32_bf16(Ai, br8, accI[os], 0, 0, 0);
      }
    }
  }

  // ---- tree-reduce partial sums across the 4 waves
  if (w >= 2) {
#pragma unroll
    for (int os = 0; os < 4; ++os) {
      red[w - 2][l][os] = accR[os];
      red[w - 2][l][4 + os] = accI[os];
    }
  }
  __syncthreads();
  if (w < 2) {
#pragma unroll
    for (int os = 0; os < 4; ++os) {
      accR[os] += red[w][l][os];
      accI[os] += red[w][l][4 + os];
    }
  }
  __syncthreads();
  if (w == 1) {
#pragma unroll
    for (int os = 0; os < 4; ++os) {
      red[0][l][os] = accR[os];
      red[0][l][4 + os] = accI[os];
    }
  }
  __syncthreads();
  if (w == 0) {
#pragma unroll
    for (int os = 0; os < 4; ++os) {
      accR[os] += red[0][l][os];
      accI[os] += red[0][l][4 + os];
      int oc = os * 16 + lane15;
#pragma unroll
      for (int r = 0; r < 4; ++r) {
        size_t oidx = ((size_t)b * 512 + it * 16 + quad * 4 + r) * 64 + oc;
        out_r[oidx] = accR[os][r];
        out_i[oidx] = accI[os][r];
      }
    }
  }
}

extern "C" void kernel_launch(void* const* d_in, const int* in_sizes, int n_in,
                              void* d_out, int out_size, void* d_ws, size_t ws_size,
                              hipStream_t stream) {
  const float* Xr = (const float*)d_in[0];
  const float* Xi = (const float*)d_in[1];
  const float* lapr = (const float*)d_in[2];
  const float* lapi = (const float*)d_in[3];
  const float* War = (const float*)d_in[4];
  const float* Wai = (const float*)d_in[5];
  const float* bar = (const float*)d_in[6];
  const float* bai = (const float*)d_in[7];
  const float* modb = (const float*)d_in[8];
  const float* Wr = (const float*)d_in[9];
  const float* Wi = (const float*)d_in[10];

  // ws layout: s4 384KB | stats 384KB | sj2 192KB | yfrag 30MB  (total ~31.7MB)
  char* wsb = (char*)d_ws;
  float4* s4 = (float4*)wsb;
  float4* stats = (float4*)(wsb + 393216);
  float2* sj2 = (float2*)(wsb + 786432);
  u32x4* yfrag = (u32x4*)(wsb + 983040);

  float* out_r = (float*)d_out;
  float* out_i = out_r + (size_t)48 * 512 * 64;

  k_s<<<768, 256, 0, stream>>>(Xr, Xi, War, Wai, s4, sj2);
  k_stats<<<768, 256, 0, stream>>>(s4, sj2, bar, bai, modb, stats);
  k_y<<<240, 256, 0, stream>>>(Xr, Xi, Wr, Wi, yfrag);
  k_main<<<1536, 256, 0, stream>>>(lapr, lapi, s4, stats, sj2, yfrag,
                                   bar, bai, modb, out_r, out_i);
}

// Round 8
// 190.806 us; speedup vs baseline: 2.7659x; 1.0447x over previous
//
#include <hip/hip_runtime.h>

#define EPSF 1e-9f

typedef __attribute__((ext_vector_type(8))) short short8;
typedef __attribute__((ext_vector_type(4))) float f32x4;
typedef __attribute__((ext_vector_type(4))) unsigned int u32x4;
typedef __attribute__((ext_vector_type(2))) unsigned int u32x2;

__device__ __forceinline__ unsigned pkbf(float lo, float hi) {
  unsigned r;
  asm("v_cvt_pk_bf16_f32 %0, %1, %2" : "=v"(r) : "v"(lo), "v"(hi));
  return r;
}
__device__ __forceinline__ short8 mk8(unsigned a, unsigned b, unsigned c, unsigned d) {
  u32x4 u = {a, b, c, d};
  return __builtin_bit_cast(short8, u);
}

// ---------------- k_s: s[b,n] = (si_r, si_i, sj_r, sj_i); 8 lanes per row
__global__ __launch_bounds__(256) void k_s(
    const float* __restrict__ Xr, const float* __restrict__ Xi,
    const float* __restrict__ War, const float* __restrict__ Wai,
    float4* __restrict__ s4, float2* __restrict__ sj2)
{
  int t = threadIdx.x;
  int nf = blockIdx.x * 32 + (t >> 3);   // flat b*512+n
  int c0 = (t & 7) * 8;
  const f32x4* xr = (const f32x4*)(Xr + (size_t)nf * 64 + c0);
  const f32x4* xi = (const f32x4*)(Xi + (size_t)nf * 64 + c0);
  const f32x4* w1r = (const f32x4*)(War + c0);
  const f32x4* w2r = (const f32x4*)(War + 64 + c0);
  const f32x4* w1i = (const f32x4*)(Wai + c0);
  const f32x4* w2i = (const f32x4*)(Wai + 64 + c0);
  float sir = 0.f, sii = 0.f, sjr = 0.f, sji = 0.f;
#pragma unroll
  for (int h = 0; h < 2; ++h) {
    f32x4 a = xr[h], bb = xi[h];
    f32x4 u1r = w1r[h], u1i = w1i[h], u2r = w2r[h], u2i = w2i[h];
#pragma unroll
    for (int e = 0; e < 4; ++e) {
      sir += a[e] * u1r[e] - bb[e] * u1i[e];
      sii += a[e] * u1i[e] + bb[e] * u1r[e];
      sjr += a[e] * u2r[e] - bb[e] * u2i[e];
      sji += a[e] * u2i[e] + bb[e] * u2r[e];
    }
  }
#pragma unroll
  for (int off = 1; off < 8; off <<= 1) {
    sir += __shfl_xor(sir, off);
    sii += __shfl_xor(sii, off);
    sjr += __shfl_xor(sjr, off);
    sji += __shfl_xor(sji, off);
  }
  if ((t & 7) == 0) {
    s4[nf] = make_float4(sir, sii, sjr, sji);
    sj2[nf] = make_float2(sjr, sji);
  }
}

// ---------------- k_stats: per-(b,i) (max_r, 1/sum_r, max_i, 1/sum_i)
__global__ __launch_bounds__(256) void k_stats(
    const float4* __restrict__ s4, const float2* __restrict__ sj2,
    const float* __restrict__ bar, const float* __restrict__ bai,
    const float* __restrict__ modbp, float4* __restrict__ stats)
{
  __shared__ float2 sh[512];
  int t = threadIdx.x;
  int b = blockIdx.x >> 4;
  int i0 = (blockIdx.x & 15) * 32;
  sh[t] = sj2[(size_t)b * 512 + t];
  sh[t + 256] = sj2[(size_t)b * 512 + t + 256];
  __syncthreads();
  float ba_r = bar[0], ba_i = bai[0], modb = modbp[0];
  int i = i0 + (t >> 3), jl = t & 7;
  float4 sv = s4[(size_t)b * 512 + i];
  float sirb = sv.x + ba_r, siib = sv.y + ba_i;
  float mr = -1e30f, mi = -1e30f;
  for (int jj = 0; jj < 64; ++jj) {
    float2 sj = sh[jl * 64 + jj];
    float scr = sirb + sj.x, sci = siib + sj.y;
    float mag = sqrtf(scr * scr + sci * sci);
    float sc = fmaxf(mag + modb, 0.f) * __builtin_amdgcn_rcpf(mag + EPSF);
    mr = fmaxf(mr, scr * sc);
    mi = fmaxf(mi, sci * sc);
  }
#pragma unroll
  for (int off = 1; off < 8; off <<= 1) {
    mr = fmaxf(mr, __shfl_xor(mr, off));
    mi = fmaxf(mi, __shfl_xor(mi, off));
  }
  float er = 0.f, ei = 0.f;
  for (int jj = 0; jj < 64; ++jj) {
    float2 sj = sh[jl * 64 + jj];
    float scr = sirb + sj.x, sci = siib + sj.y;
    float mag = sqrtf(scr * scr + sci * sci);
    float sc = fmaxf(mag + modb, 0.f) * __builtin_amdgcn_rcpf(mag + EPSF);
    er += __expf(scr * sc - mr);
    ei += __expf(sci * sc - mi);
  }
#pragma unroll
  for (int off = 1; off < 8; off <<= 1) {
    er += __shfl_xor(er, off);
    ei += __shfl_xor(ei, off);
  }
  if (jl == 0)
    stats[(size_t)b * 512 + i] = make_float4(mr, 1.f / er, mi, 1.f / ei);
}

// ---------------- k_y: Y[b,k] = X[b] @ W[k] (complex), written to ws in
// B-fragment layout, bf16: per (b,k): 128 lines (part*64 + js*4 + os) x 64 lanes x 16B
__global__ __launch_bounds__(256) void k_y(
    const float* __restrict__ Xr, const float* __restrict__ Xi,
    const float* __restrict__ Wr, const float* __restrict__ Wi,
    u32x4* __restrict__ yfrag)
{
  __shared__ __align__(16) short WtR[64 * 72];     // [o][c] pad 72
  __shared__ __align__(16) short WtI[64 * 72];
  __shared__ __align__(16) short Yt[4][2][64 * 24]; // per-wave [o][jj] pad 24
  int bk = blockIdx.x;
  int b = bk / 5, k = bk % 5;
  int t = threadIdx.x;
  {
    int o = t & 63, cbase = (t >> 6) * 16;
    const float* wr = Wr + (size_t)k * 4096;
    const float* wi = Wi + (size_t)k * 4096;
#pragma unroll
    for (int cc = 0; cc < 16; cc += 2) {
      int c = cbase + cc;
      *(unsigned*)&WtR[o * 72 + c] = pkbf(wr[c * 64 + o], wr[(c + 1) * 64 + o]);
      *(unsigned*)&WtI[o * 72 + c] = pkbf(wi[c * 64 + o], wi[(c + 1) * 64 + o]);
    }
  }
  __syncthreads();
  int w = t >> 6, l = t & 63;
  int lane15 = l & 15, quad = l >> 4;
  short* ytR = &Yt[w][0][0];
  short* ytI = &Yt[w][1][0];
  for (int qq = 0; qq < 8; ++qq) {
    int q = w * 8 + qq;
    int j = q * 16 + lane15;
    const f32x4* pxr = (const f32x4*)(Xr + ((size_t)b * 512 + j) * 64 + quad * 8);
    const f32x4* pxi = (const f32x4*)(Xi + ((size_t)b * 512 + j) * 64 + quad * 8);
    f32x4 xr0 = pxr[0], xr1 = pxr[1], xr8 = pxr[8], xr9 = pxr[9];
    f32x4 xi0 = pxi[0], xi1 = pxi[1], xi8 = pxi[8], xi9 = pxi[9];
    short8 axr[2], axi[2];
    axr[0] = mk8(pkbf(xr0[0], xr0[1]), pkbf(xr0[2], xr0[3]), pkbf(xr1[0], xr1[1]), pkbf(xr1[2], xr1[3]));
    axr[1] = mk8(pkbf(xr8[0], xr8[1]), pkbf(xr8[2], xr8[3]), pkbf(xr9[0], xr9[1]), pkbf(xr9[2], xr9[3]));
    axi[0] = mk8(pkbf(xi0[0], xi0[1]), pkbf(xi0[2], xi0[3]), pkbf(xi1[0], xi1[1]), pkbf(xi1[2], xi1[3]));
    axi[1] = mk8(pkbf(xi8[0], xi8[1]), pkbf(xi8[2], xi8[3]), pkbf(xi9[0], xi9[1]), pkbf(xi9[2], xi9[3]));
    f32x4 aR1[4], aR2[4], aI[4];
#pragma unroll
    for (int os = 0; os < 4; ++os) {
      aR1[os] = f32x4{0.f, 0.f, 0.f, 0.f};
      aR2[os] = f32x4{0.f, 0.f, 0.f, 0.f};
      aI[os] = f32x4{0.f, 0.f, 0.f, 0.f};
    }
#pragma unroll
    for (int kc = 0; kc < 2; ++kc) {
#pragma unroll
      for (int os = 0; os < 4; ++os) {
        int widx = (os * 16 + lane15) * 72 + kc * 32 + quad * 8;
        short8 wrF = *(const short8*)&WtR[widx];
        short8 wiF = *(const short8*)&WtI[widx];
        aR1[os] = __builtin_amdgcn_mfma_f32_16x16x32_bf16(axr[kc], wrF, aR1[os], 0, 0, 0);
        aR2[os] = __builtin_amdgcn_mfma_f32_16x16x32_bf16(axi[kc], wiF, aR2[os], 0, 0, 0);
        aI[os]  = __builtin_amdgcn_mfma_f32_16x16x32_bf16(axr[kc], wiF, aI[os], 0, 0, 0);
        aI[os]  = __builtin_amdgcn_mfma_f32_16x16x32_bf16(axi[kc], wrF, aI[os], 0, 0, 0);
      }
    }
#pragma unroll
    for (int os = 0; os < 4; ++os) {
      f32x4 R = aR1[os] - aR2[os];
      f32x4 I = aI[os];
      int ya = (os * 16 + lane15) * 24 + quad * 4;
      *(u32x2*)&ytR[ya] = u32x2{pkbf(R[0], R[1]), pkbf(R[2], R[3])};
      *(u32x2*)&ytI[ya] = u32x2{pkbf(I[0], I[1]), pkbf(I[2], I[3])};
    }
#pragma unroll
    for (int part = 0; part < 2; ++part) {
      const short* yt = part ? ytI : ytR;
#pragma unroll
      for (int h = 0; h < 2; ++h) {
        short8 unit = *(const short8*)&yt[l * 24 + h * 8];
        size_t line = (((size_t)(b * 5 + k) * 2 + part) * 16 + (q >> 1)) * 4 + (l >> 4);
        size_t idx = line * 64 + ((q & 1) * 2 + h) * 16 + (l & 15);
        yfrag[idx] = __builtin_bit_cast(u32x4, unit);
      }
    }
  }
}

// ---------------- k_main v7: round-6 body (known-good), with the scheduler's
// occupancy TARGET pinned to 2 waves/EU via amdgpu_waves_per_eu(2,2). This lets
// the allocator keep all 20 lap-load destinations (80 VGPRs) live at once, so
// the per-js-step loads issue back-to-back: one HBM round-trip per js-step
// instead of ~10 serialized ones (round 6: VGPR_Count=84 proved dest reuse).
__global__ __launch_bounds__(256) __attribute__((amdgpu_waves_per_eu(2, 2)))
void k_main(
    const float* __restrict__ lapr, const float* __restrict__ lapi,
    const float4* __restrict__ s4, const float4* __restrict__ stats,
    const float2* __restrict__ sj2, const u32x4* __restrict__ yfrag,
    const float* __restrict__ bar, const float* __restrict__ bai,
    const float* __restrict__ modbp,
    float* __restrict__ out_r, float* __restrict__ out_i)
{
  __shared__ __align__(16) f32x4 red[2][64][8];   // 16 KB tree-reduce buffer

  const int g = blockIdx.x;
  const int b = (g & 7) + ((g >> 8) << 3);   // XCD swizzle (1536 = 8*192, bijective)
  const int it = (g >> 3) & 31;
  const int t = threadIdx.x;
  const int w = t >> 6;                      // wave = js-slice 0..3
  const int l = t & 63;
  const int lane15 = l & 15, quad = l >> 4;
  const int gi = it * 16 + lane15;

  float ba_r = bar[0], ba_i = bai[0], modb = modbp[0];
  float4 sv = s4[(size_t)b * 512 + gi];
  float4 st = stats[(size_t)b * 512 + gi];
  float sirb = sv.x + ba_r, siib = sv.y + ba_i;
  float maxr = st.x, rsr = st.y, maxi = st.z, rsi = st.w;

  f32x4 accR[4], accI[4];
#pragma unroll
  for (int os = 0; os < 4; ++os) {
    accR[os] = f32x4{0.f, 0.f, 0.f, 0.f};
    accI[os] = f32x4{0.f, 0.f, 0.f, 0.f};
  }

  const size_t NN = (size_t)512 * 512;
  const float* lapr_b = lapr + ((size_t)b * 5 * 512 + gi) * 512;
  const float* lapi_b = lapi + ((size_t)b * 5 * 512 + gi) * 512;
  const u32x4* yb = yfrag + (size_t)b * 5 * 8192 + l;

  for (int jsw = 0; jsw < 4; ++jsw) {
    const int js = w * 4 + jsw;
    const int jq = js * 32 + quad * 8;

    // --- issue sj loads, then ALL 20 lap loads (kept live together in VGPRs)
    const f32x4* sjp = (const f32x4*)(sj2 + (size_t)b * 512 + jq);
    f32x4 sjv0 = sjp[0], sjv1 = sjp[1], sjv2 = sjp[2], sjv3 = sjp[3];

    f32x4 LR[5][2], LI[5][2];
#pragma unroll
    for (int k = 0; k < 5; ++k) {
      const f32x4* pr = (const f32x4*)(lapr_b + (size_t)k * NN + jq);
      const f32x4* pi_ = (const f32x4*)(lapi_b + (size_t)k * NN + jq);
      LR[k][0] = __builtin_nontemporal_load(pr);
      LR[k][1] = __builtin_nontemporal_load(pr + 1);
      LI[k][0] = __builtin_nontemporal_load(pi_);
      LI[k][1] = __builtin_nontemporal_load(pi_ + 1);
    }
    __builtin_amdgcn_sched_barrier(0);   // pin load issue above the a-compute

    // --- a-compute: independent of lap loads, runs under their latency
    float sjr[8] = {sjv0[0], sjv0[2], sjv1[0], sjv1[2], sjv2[0], sjv2[2], sjv3[0], sjv3[2]};
    float sjimag[8] = {sjv0[1], sjv0[3], sjv1[1], sjv1[3], sjv2[1], sjv2[3], sjv3[1], sjv3[3]};
    float ar[8], ai[8];
#pragma unroll
    for (int e = 0; e < 8; ++e) {
      float scr = sirb + sjr[e];
      float sci = siib + sjimag[e];
      float mag = __builtin_amdgcn_sqrtf(fmaf(scr, scr, sci * sci));
      float sc = fmaxf(mag + modb, 0.f) * __builtin_amdgcn_rcpf(mag + EPSF);
      ar[e] = __expf(fmaf(scr, sc, -maxr)) * rsr;
      ai[e] = __expf(fmaf(sci, sc, -maxi)) * rsi;
    }

    // --- per k: pack A (short-lived), load B (L2), 16 MFMA
#pragma unroll
    for (int k = 0; k < 5; ++k) {
      float lrv[8], liv[8];
#pragma unroll
      for (int e = 0; e < 4; ++e) {
        lrv[e]     = LR[k][0][e] * ar[e]     - LI[k][0][e] * ai[e];
        liv[e]     = LR[k][0][e] * ai[e]     + LI[k][0][e] * ar[e];
        lrv[4 + e] = LR[k][1][e] * ar[4 + e] - LI[k][1][e] * ai[4 + e];
        liv[4 + e] = LR[k][1][e] * ai[4 + e] + LI[k][1][e] * ar[4 + e];
      }
      unsigned p0 = pkbf(lrv[0], lrv[1]), p1 = pkbf(lrv[2], lrv[3]);
      unsigned p2 = pkbf(lrv[4], lrv[5]), p3 = pkbf(lrv[6], lrv[7]);
      unsigned q0 = pkbf(liv[0], liv[1]), q1 = pkbf(liv[2], liv[3]);
      unsigned q2 = pkbf(liv[4], liv[5]), q3 = pkbf(liv[6], liv[7]);
      short8 Ar = mk8(p0, p1, p2, p3);
      short8 Ai = mk8(q0, q1, q2, q3);
      short8 An = mk8(q0 ^ 0x80008000u, q1 ^ 0x80008000u,
                      q2 ^ 0x80008000u, q3 ^ 0x80008000u);

      const u32x4* yk = yb + (size_t)k * 8192 + (size_t)(js * 4) * 64;
#pragma unroll
      for (int os = 0; os < 4; ++os) {
        short8 br8 = __builtin_bit_cast(short8, yk[os * 64]);
        short8 bi8 = __builtin_bit_cast(short8, yk[4096 + os * 64]);
        accR[os] = __builtin_amdgcn_mfma_f32_16x16x32_bf16(Ar, br8, accR[os], 0, 0, 0);
        accR[os] = __builtin_amdgcn_mfma_f32_16x16x32_bf16(An, bi8, accR[os], 0, 0, 0);
        accI[os] = __builtin_amdgcn_mfma_f32_16x16x32_bf16(Ar, bi8, accI[os], 0, 0, 0);
        accI[os] = __builtin_amdgcn_mfma_f32_16x16x32_bf16(Ai, br8, accI[os], 0, 0, 0);
      }
    }
  }

  // ---- tree-reduce partial sums across the 4 waves
  if (w >= 2) {
#pragma unroll
    for (int os = 0; os < 4; ++os) {
      red[w - 2][l][os] = accR[os];
      red[w - 2][l][4 + os] = accI[os];
    }
  }
  __syncthreads();
  if (w < 2) {
#pragma unroll
    for (int os = 0; os < 4; ++os) {
      accR[os] += red[w][l][os];
      accI[os] += red[w][l][4 + os];
    }
  }
  __syncthreads();
  if (w == 1) {
#pragma unroll
    for (int os = 0; os < 4; ++os) {
      red[0][l][os] = accR[os];
      red[0][l][4 + os] = accI[os];
    }
  }
  __syncthreads();
  if (w == 0) {
#pragma unroll
    for (int os = 0; os < 4; ++os) {
      accR[os] += red[0][l][os];
      accI[os] += red[0][l][4 + os];
      int oc = os * 16 + lane15;
#pragma unroll
      for (int r = 0; r < 4; ++r) {
        size_t oidx = ((size_t)b * 512 + it * 16 + quad * 4 + r) * 64 + oc;
        out_r[oidx] = accR[os][r];
        out_i[oidx] = accI[os][r];
      }
    }
  }
}

extern "C" void kernel_launch(void* const* d_in, const int* in_sizes, int n_in,
                              void* d_out, int out_size, void* d_ws, size_t ws_size,
                              hipStream_t stream) {
  const float* Xr = (const float*)d_in[0];
  const float* Xi = (const float*)d_in[1];
  const float* lapr = (const float*)d_in[2];
  const float* lapi = (const float*)d_in[3];
  const float* War = (const float*)d_in[4];
  const float* Wai = (const float*)d_in[5];
  const float* bar = (const float*)d_in[6];
  const float* bai = (const float*)d_in[7];
  const float* modb = (const float*)d_in[8];
  const float* Wr = (const float*)d_in[9];
  const float* Wi = (const float*)d_in[10];

  // ws layout: s4 384KB | stats 384KB | sj2 192KB | yfrag 30MB  (total ~31.7MB)
  char* wsb = (char*)d_ws;
  float4* s4 = (float4*)wsb;
  float4* stats = (float4*)(wsb + 393216);
  float2* sj2 = (float2*)(wsb + 786432);
  u32x4* yfrag = (u32x4*)(wsb + 983040);

  float* out_r = (float*)d_out;
  float* out_i = out_r + (size_t)48 * 512 * 64;

  k_s<<<768, 256, 0, stream>>>(Xr, Xi, War, Wai, s4, sj2);
  k_stats<<<768, 256, 0, stream>>>(s4, sj2, bar, bai, modb, stats);
  k_y<<<240, 256, 0, stream>>>(Xr, Xi, Wr, Wi, yfrag);
  k_main<<<1536, 256, 0, stream>>>(lapr, lapi, s4, stats, sj2, yfrag,
                                   bar, bai, modb, out_r, out_i);
}